// Round 1
// baseline (314.587 us; speedup 1.0000x reference)
//
#include <hip/hip_runtime.h>
#include <math.h>

// ExpertGate: scores = sigmoid(X @ W^T); top-8 routing with bias-for-selection,
// gather un-biased scores, renormalize * 2.5. Outputs: weights fp32 (N*8) then
// indices-as-float (N*8), concatenated in d_out.

#define D_DIM 2048
#define E_DIM 64
#define TOPK 8
#define TM 32        // tokens per block
#define BK 64        // k-chunk
#define XS_STRIDE 68 // pad: 16B-aligned, breaks pow2 bank stride
#define WS_STRIDE 68
#define SC_STRIDE 65

__global__ __launch_bounds__(256) void expert_gate_kernel(
    const float* __restrict__ x,      // (N, 2048)
    const float* __restrict__ w,      // (64, 2048)
    const float* __restrict__ bias,   // (64,)
    float* __restrict__ out,          // N*8 weights, then N*8 indices-as-float
    int N)
{
    __shared__ float Xs[TM * XS_STRIDE];
    __shared__ float Ws[E_DIM * WS_STRIDE];
    __shared__ float Sc[TM * SC_STRIDE];

    const int t   = threadIdx.x;
    const int tx  = t & 15;   // expert group: experts tx + 16*j, j=0..3
    const int ty  = t >> 4;   // token group:  tokens  ty + 16*i, i=0..1
    const int tok0 = blockIdx.x * TM;
    const int lane = t & 63;

    // per-lane expert bias for the top-k phase (lane == expert there)
    const float my_bias = bias[lane];

    float acc[2][4] = {{0.f,0.f,0.f,0.f},{0.f,0.f,0.f,0.f}};

    for (int k0 = 0; k0 < D_DIM; k0 += BK) {
        // ---- stage X tile: 32 rows x 64 floats (512 float4, 2/thread) ----
        {
            int f = t;
            int row = f >> 4, col = (f & 15) << 2;
            float4 v = *reinterpret_cast<const float4*>(
                &x[(size_t)(tok0 + row) * D_DIM + k0 + col]);
            *reinterpret_cast<float4*>(&Xs[row * XS_STRIDE + col]) = v;
            f = t + 256;
            row = f >> 4; col = (f & 15) << 2;
            v = *reinterpret_cast<const float4*>(
                &x[(size_t)(tok0 + row) * D_DIM + k0 + col]);
            *reinterpret_cast<float4*>(&Xs[row * XS_STRIDE + col]) = v;
        }
        // ---- stage W tile: 64 rows x 64 floats (1024 float4, 4/thread) ----
        #pragma unroll
        for (int i = 0; i < 4; ++i) {
            int f = t + i * 256;
            int row = f >> 4, col = (f & 15) << 2;
            float4 v = *reinterpret_cast<const float4*>(
                &w[(size_t)row * D_DIM + k0 + col]);
            *reinterpret_cast<float4*>(&Ws[row * WS_STRIDE + col]) = v;
        }
        __syncthreads();

        // ---- compute: each thread 2 tokens x 4 experts ----
        #pragma unroll
        for (int kk = 0; kk < BK; kk += 4) {
            float4 a0 = *reinterpret_cast<const float4*>(&Xs[ty * XS_STRIDE + kk]);
            float4 a1 = *reinterpret_cast<const float4*>(&Xs[(ty + 16) * XS_STRIDE + kk]);
            #pragma unroll
            for (int j = 0; j < 4; ++j) {
                float4 b = *reinterpret_cast<const float4*>(
                    &Ws[(tx + 16 * j) * WS_STRIDE + kk]);
                // sequential fp32 accumulation over k (tracks np ref closely)
                acc[0][j] = fmaf(a0.x, b.x, acc[0][j]);
                acc[0][j] = fmaf(a0.y, b.y, acc[0][j]);
                acc[0][j] = fmaf(a0.z, b.z, acc[0][j]);
                acc[0][j] = fmaf(a0.w, b.w, acc[0][j]);
                acc[1][j] = fmaf(a1.x, b.x, acc[1][j]);
                acc[1][j] = fmaf(a1.y, b.y, acc[1][j]);
                acc[1][j] = fmaf(a1.z, b.z, acc[1][j]);
                acc[1][j] = fmaf(a1.w, b.w, acc[1][j]);
            }
        }
        __syncthreads();
    }

    // ---- sigmoid, park scores in LDS ----
    #pragma unroll
    for (int i = 0; i < 2; ++i) {
        #pragma unroll
        for (int j = 0; j < 4; ++j) {
            float s = 1.0f / (1.0f + expf(-acc[i][j]));
            Sc[(ty + 16 * i) * SC_STRIDE + (tx + 16 * j)] = s;
        }
    }
    __syncthreads();

    // ---- top-8 per token: lane == expert; wave handles 8 tokens ----
    const int wave = t >> 6;  // 0..3
    for (int r = 0; r < 8; ++r) {
        const int tok = wave * 8 + r;
        const float s = Sc[tok * SC_STRIDE + lane];  // original score
        float rv = s + my_bias;                      // routing score
        float outw = 0.f;
        int   outi = 0;
        float ssum = 0.f;
        #pragma unroll
        for (int sel = 0; sel < TOPK; ++sel) {
            float v = rv;
            int   vi = lane;
            // 64-lane butterfly lexicographic max (ties -> lower index)
            #pragma unroll
            for (int off = 1; off < 64; off <<= 1) {
                float ov = __shfl_xor(v, off);
                int   oi = __shfl_xor(vi, off);
                if (ov > v || (ov == v && oi < vi)) { v = ov; vi = oi; }
            }
            float cs = __shfl(s, vi);  // original (un-biased) score of winner
            ssum += cs;
            if (lane == sel) { outw = cs; outi = vi; }
            if (lane == vi) rv = -INFINITY;
        }
        if (lane < TOPK) {
            const size_t base = (size_t)(tok0 + tok) * TOPK + lane;
            out[base] = outw / (ssum + 1e-8f) * 2.5f;
            out[(size_t)N * TOPK + base] = (float)outi;
        }
    }
}

extern "C" void kernel_launch(void* const* d_in, const int* in_sizes, int n_in,
                              void* d_out, int out_size, void* d_ws, size_t ws_size,
                              hipStream_t stream) {
    const float* x    = (const float*)d_in[0];
    const float* w    = (const float*)d_in[1];
    const float* bias = (const float*)d_in[2];
    float* out = (float*)d_out;
    const int N = in_sizes[0] / D_DIM;  // 16384
    const int grid = N / TM;            // 512
    expert_gate_kernel<<<grid, 256, 0, stream>>>(x, w, bias, out, N);
}